// Round 3
// baseline (199.511 us; speedup 1.0000x reference)
//
#include <hip/hip_runtime.h>
#include <hip/hip_bf16.h>
#include <cstdint>

#define N_SRC 100000
#define N_DST 25000
#define N_EDGE 300000
// D_IN = D_HID = D_OUT = 256, concat K = 512

typedef float f32x4 __attribute__((ext_vector_type(4)));
typedef __bf16 bf16x8 __attribute__((ext_vector_type(8)));

typedef const __attribute__((address_space(1))) void gv_t;
typedef __attribute__((address_space(3))) void lv_t;

__device__ __forceinline__ unsigned short f2bf(float f) {
    union { float f; unsigned int u; } v; v.f = f;
    unsigned int u = v.u;
    u += 0x7FFFu + ((u >> 16) & 1u);   // RNE; inputs finite
    return (unsigned short)(u >> 16);
}
__device__ __forceinline__ float bf2f(unsigned int bits16) {
    union { unsigned int u; float f; } v; v.u = bits16 << 16;
    return v.f;
}

__device__ __forceinline__ void gload16(uint4& d, const void* p) {
    asm volatile("global_load_dwordx4 %0, %1, off" : "=v"(d) : "v"(p) : "memory");
}

#define VMWAIT(N) do { asm volatile("s_waitcnt vmcnt(" #N ")" ::: "memory"); \
                       __builtin_amdgcn_sched_barrier(0); } while (0)
#define BAR() __builtin_amdgcn_s_barrier()

// ---- cast + transpose weights: Qt[n][k] = bf16(Q_w[k][n]), Wt[n][k] = bf16(W_w[k][n])
__global__ void cast_weights(const float* __restrict__ Qw, const float* __restrict__ Ww,
                             unsigned short* __restrict__ Qt, unsigned short* __restrict__ Wt) {
    int i = blockIdx.x * blockDim.x + threadIdx.x;
    if (i < 256 * 256) {
        int n = i >> 8, k = i & 255;
        Qt[n * 256 + k] = f2bf(Qw[k * 256 + n]);
    } else if (i < 256 * 256 + 512 * 256) {
        int j = i - 256 * 256;
        int n = j >> 9, k = j & 511;
        Wt[n * 512 + k] = f2bf(Ww[k * 256 + n]);
    }
}

// ---- CSR build
__global__ void hist_kernel(const int* __restrict__ dst_idx, int* __restrict__ counts) {
    int i = blockIdx.x * blockDim.x + threadIdx.x;
    if (i < N_EDGE) atomicAdd(&counts[dst_idx[i]], 1);
}

__global__ __launch_bounds__(1024) void scan_kernel(const int* __restrict__ counts,
                                                    int* __restrict__ offsets, int n) {
    __shared__ int wsum[16];
    const int t = threadIdx.x;
    const int wid = t >> 6, lane = t & 63;
    int carry = 0;
    if (t == 0) offsets[0] = 0;
    for (int base = 0; base < n; base += 1024) {
        int x = (base + t < n) ? counts[base + t] : 0;
        #pragma unroll
        for (int off = 1; off < 64; off <<= 1) {
            int y = __shfl_up(x, off, 64);
            if (lane >= off) x += y;
        }
        if (lane == 63) wsum[wid] = x;
        __syncthreads();
        if (t < 16) {
            int w = wsum[t];
            #pragma unroll
            for (int off = 1; off < 16; off <<= 1) {
                int y = __shfl_up(w, off, 64);
                if (t >= off) w += y;
            }
            wsum[t] = w;
        }
        __syncthreads();
        int pre = (wid > 0) ? wsum[wid - 1] : 0;
        int incl = carry + pre + x;
        if (base + t < n) offsets[base + t + 1] = incl;
        carry += wsum[15];
        __syncthreads();
    }
}

__global__ void scatter_kernel(const int* __restrict__ dst_idx, const int* __restrict__ offsets,
                               int* __restrict__ counts, int* __restrict__ edge_list) {
    int i = blockIdx.x * blockDim.x + threadIdx.x;
    if (i < N_EDGE) {
        int d = dst_idx[i];
        int pos = offsets[d] + (atomicSub(&counts[d], 1) - 1);
        edge_list[pos] = i;
    }
}

// ---- pipelined GEMM: C = relu(A @ Bt^T + bias), optional row-L2-norm epilogue.
// Tile 64(M) x 256(N); 4 waves, wave w owns cols w*64..+63. 8 k-tiles of 8KB A.
// A staged via global_load_lds into a 4-buffer LDS ring (linear dest, source
// pre-XOR-swizzled per 128B row; reads use the same XOR -> conflict-free).
// B held in regs (half-K chunks of 4 kf = 64 VGPR), loaded via asm so all
// vmcnt counting is manual; counted vmcnt(4), raw s_barrier, never drain to 0.
template<int KDIM, bool A_F32, bool NORM>
__global__ __launch_bounds__(256, 2) void gemm_pipe(
    const float* __restrict__ Af, const unsigned short* __restrict__ Ab,
    const unsigned short* __restrict__ Bt, const float* __restrict__ bias,
    unsigned short* __restrict__ Cb, float* __restrict__ Cf, int M)
{
    __shared__ __align__(16) unsigned char Abuf[4][8192];
    __shared__ float norml[4][64];

    const int tid = threadIdx.x;
    const int wv = tid >> 6, lane = tid & 63;
    const int g = lane >> 4, cl = lane & 15;
    const int m0 = blockIdx.x * 64;
    const int bn0 = wv * 64;

    uint4 bU[4][4];      // B frags: [ni][kf-slot], one half-K chunk
    f32x4 acc[4][4];
    #pragma unroll
    for (int i = 0; i < 4; ++i)
        #pragma unroll
        for (int j = 0; j < 4; ++j)
            acc[i][j] = (f32x4){0.f, 0.f, 0.f, 0.f};

#define BLOAD(cch) do { \
    _Pragma("unroll") \
    for (int ni = 0; ni < 4; ++ni) { \
        _Pragma("unroll") \
        for (int q = 0; q < 4; ++q) \
            gload16(bU[ni][q], Bt + (size_t)(bn0 + ni * 16 + cl) * KDIM + ((cch) * 4 + q) * 32 + g * 8); \
    } } while (0)

#define STAGE(t) do { \
    _Pragma("unroll") \
    for (int j = 0; j < 2; ++j) { \
        const int chunk = wv * 2 + j; \
        const int row = chunk * 8 + (lane >> 3); \
        int grow = m0 + row; if (grow > M - 1) grow = M - 1; \
        const int sws = (lane & 7) ^ (row & 7); \
        if constexpr (A_F32) { \
            const float* gp = Af + (size_t)grow * KDIM + (t) * 32 + sws * 4; \
            __builtin_amdgcn_global_load_lds((gv_t*)gp, (lv_t*)&Abuf[(t) & 3][chunk * 1024], 16, 0, 0); \
        } else { \
            const unsigned short* gp = Ab + (size_t)grow * KDIM + (t) * 64 + sws * 8; \
            __builtin_amdgcn_global_load_lds((gv_t*)gp, (lv_t*)&Abuf[(t) & 3][chunk * 1024], 16, 0, 0); \
        } \
    } } while (0)

#define COMPUTE(t) do { \
    if constexpr (A_F32) { \
        _Pragma("unroll") \
        for (int mi = 0; mi < 4; ++mi) { \
            const int row = mi * 16 + cl; \
            const f32x4 lo = *(const f32x4*)&Abuf[(t) & 3][row * 128 + ((g * 2 + 0) ^ (cl & 7)) * 16]; \
            const f32x4 hi = *(const f32x4*)&Abuf[(t) & 3][row * 128 + ((g * 2 + 1) ^ (cl & 7)) * 16]; \
            bf16x8 af; \
            af[0] = (__bf16)lo[0]; af[1] = (__bf16)lo[1]; af[2] = (__bf16)lo[2]; af[3] = (__bf16)lo[3]; \
            af[4] = (__bf16)hi[0]; af[5] = (__bf16)hi[1]; af[6] = (__bf16)hi[2]; af[7] = (__bf16)hi[3]; \
            _Pragma("unroll") \
            for (int ni = 0; ni < 4; ++ni) \
                acc[mi][ni] = __builtin_amdgcn_mfma_f32_16x16x32_bf16( \
                    af, __builtin_bit_cast(bf16x8, bU[ni][(t) & 3]), acc[mi][ni], 0, 0, 0); \
        } \
    } else { \
        _Pragma("unroll") \
        for (int ks = 0; ks < 2; ++ks) { \
            _Pragma("unroll") \
            for (int mi = 0; mi < 4; ++mi) { \
                const int row = mi * 16 + cl; \
                const bf16x8 af = *(const bf16x8*)&Abuf[(t) & 3][row * 128 + (((ks) * 4 + g) ^ (cl & 7)) * 16]; \
                _Pragma("unroll") \
                for (int ni = 0; ni < 4; ++ni) \
                    acc[mi][ni] = __builtin_amdgcn_mfma_f32_16x16x32_bf16( \
                        af, __builtin_bit_cast(bf16x8, bU[ni][((t) * 2 + (ks)) & 3]), acc[mi][ni], 0, 0, 0); \
            } \
        } \
    } } while (0)

    BLOAD(0);
    STAGE(0); STAGE(1); STAGE(2);

    VMWAIT(4); BAR();            // B0 + s0 landed
    STAGE(3); COMPUTE(0);
    VMWAIT(4); BAR();            // s1 landed
    STAGE(4); COMPUTE(1);
    if constexpr (A_F32) {       // K=256: B chunks at t=0,4
        VMWAIT(4); BAR(); STAGE(5); COMPUTE(2);
        VMWAIT(4); BAR(); STAGE(6); COMPUTE(3);
        VMWAIT(4); BAR(); BLOAD(1); STAGE(7); VMWAIT(2); COMPUTE(4);
        BAR(); COMPUTE(5);
        BAR(); COMPUTE(6);
        VMWAIT(0); BAR(); COMPUTE(7);
    } else {                     // K=512: B chunks at t=0,2,4,6
        VMWAIT(4); BAR(); BLOAD(1); STAGE(5); VMWAIT(2); COMPUTE(2);
        BAR(); STAGE(6); COMPUTE(3);
        VMWAIT(4); BAR(); BLOAD(2); STAGE(7); VMWAIT(2); COMPUTE(4);
        BAR(); COMPUTE(5);
        BAR(); BLOAD(3); VMWAIT(0); COMPUTE(6);
        BAR(); COMPUTE(7);
    }
#undef BLOAD
#undef STAGE
#undef COMPUTE

    float bcol[4];
    #pragma unroll
    for (int ni = 0; ni < 4; ++ni) bcol[ni] = bias[bn0 + ni * 16 + cl];

    if constexpr (!NORM) {
        #pragma unroll
        for (int mi = 0; mi < 4; ++mi) {
            int rowb = m0 + mi * 16 + g * 4;
            #pragma unroll
            for (int ni = 0; ni < 4; ++ni) {
                int col = bn0 + ni * 16 + cl;
                #pragma unroll
                for (int r = 0; r < 4; ++r) {
                    int row = rowb + r;
                    if (row < M) {
                        float v = fmaxf(acc[mi][ni][r] + bcol[ni], 0.f);
                        Cb[(size_t)row * 256 + col] = f2bf(v);
                    }
                }
            }
        }
    } else {
        float ssq[4][4];
        #pragma unroll
        for (int mi = 0; mi < 4; ++mi) {
            #pragma unroll
            for (int r = 0; r < 4; ++r) {
                float s = 0.f;
                #pragma unroll
                for (int ni = 0; ni < 4; ++ni) {
                    float v = fmaxf(acc[mi][ni][r] + bcol[ni], 0.f);
                    acc[mi][ni][r] = v;
                    s += v * v;
                }
                #pragma unroll
                for (int m = 1; m < 16; m <<= 1) s += __shfl_xor(s, m, 64);
                ssq[mi][r] = s;
            }
        }
        __syncthreads();
        if (cl == 0) {
            #pragma unroll
            for (int mi = 0; mi < 4; ++mi)
                #pragma unroll
                for (int r = 0; r < 4; ++r)
                    norml[wv][mi * 16 + g * 4 + r] = ssq[mi][r];
        }
        __syncthreads();
        #pragma unroll
        for (int mi = 0; mi < 4; ++mi) {
            int rowb = m0 + mi * 16 + g * 4;
            #pragma unroll
            for (int r = 0; r < 4; ++r) {
                int rl = mi * 16 + g * 4 + r;
                float tot = norml[0][rl] + norml[1][rl] + norml[2][rl] + norml[3][rl];
                float rn = tot > 0.f ? rsqrtf(tot) : 1.0f;
                int row = rowb + r;
                if (row < M) {
                    #pragma unroll
                    for (int ni = 0; ni < 4; ++ni) {
                        int col = bn0 + ni * 16 + cl;
                        Cf[(size_t)row * 256 + col] = acc[mi][ni][r] * rn;
                    }
                }
            }
        }
    }
}

// ---- per-dst aggregation: one wave per dst; unroll-2 on edges
__global__ __launch_bounds__(256) void aggregate_kernel(
    const unsigned short* __restrict__ nft, const float* __restrict__ h_dst,
    const float* __restrict__ weights, const int* __restrict__ src_idx,
    const int* __restrict__ edge_list, const int* __restrict__ offsets,
    unsigned short* __restrict__ xb)
{
    int d = blockIdx.x * 4 + (threadIdx.x >> 6);
    if (d >= N_DST) return;
    int lane = threadIdx.x & 63;
    int p0 = offsets[d], p1 = offsets[d + 1];
    float a0 = 0.f, a1 = 0.f, a2 = 0.f, a3 = 0.f, wsum = 0.f;
    int p = p0;
    for (; p + 1 < p1; p += 2) {
        int e0 = edge_list[p], e1 = edge_list[p + 1];
        float w0 = weights[e0], w1 = weights[e1];
        int s0 = src_idx[e0], s1 = src_idx[e1];
        uint2 v0 = *reinterpret_cast<const uint2*>(nft + (size_t)s0 * 256 + lane * 4);
        uint2 v1 = *reinterpret_cast<const uint2*>(nft + (size_t)s1 * 256 + lane * 4);
        wsum += w0 + w1;
        a0 += w0 * bf2f(v0.x & 0xffffu) + w1 * bf2f(v1.x & 0xffffu);
        a1 += w0 * bf2f(v0.x >> 16)     + w1 * bf2f(v1.x >> 16);
        a2 += w0 * bf2f(v0.y & 0xffffu) + w1 * bf2f(v1.y & 0xffffu);
        a3 += w0 * bf2f(v0.y >> 16)     + w1 * bf2f(v1.y >> 16);
    }
    if (p < p1) {
        int e = edge_list[p];
        float w = weights[e];
        int s = src_idx[e];
        wsum += w;
        uint2 v = *reinterpret_cast<const uint2*>(nft + (size_t)s * 256 + lane * 4);
        a0 += w * bf2f(v.x & 0xffffu);
        a1 += w * bf2f(v.x >> 16);
        a2 += w * bf2f(v.y & 0xffffu);
        a3 += w * bf2f(v.y >> 16);
    }
    float inv = 1.0f / fmaxf(wsum, 1.0f);
    uint2 pk;
    pk.x = (unsigned)f2bf(a0 * inv) | ((unsigned)f2bf(a1 * inv) << 16);
    pk.y = (unsigned)f2bf(a2 * inv) | ((unsigned)f2bf(a3 * inv) << 16);
    *reinterpret_cast<uint2*>(xb + (size_t)d * 512 + lane * 4) = pk;
    float4 h = *reinterpret_cast<const float4*>(h_dst + (size_t)d * 256 + lane * 4);
    uint2 q;
    q.x = (unsigned)f2bf(h.x) | ((unsigned)f2bf(h.y) << 16);
    q.y = (unsigned)f2bf(h.z) | ((unsigned)f2bf(h.w) << 16);
    *reinterpret_cast<uint2*>(xb + (size_t)d * 512 + 256 + lane * 4) = q;
}

extern "C" void kernel_launch(void* const* d_in, const int* in_sizes, int n_in,
                              void* d_out, int out_size, void* d_ws, size_t ws_size,
                              hipStream_t stream) {
    const float* h_src   = (const float*)d_in[0];
    const float* h_dst   = (const float*)d_in[1];
    const float* weights = (const float*)d_in[2];
    const float* Q_w     = (const float*)d_in[3];
    const float* Q_b     = (const float*)d_in[4];
    const float* W_w     = (const float*)d_in[5];
    const float* W_b     = (const float*)d_in[6];
    const int* src_idx   = (const int*)d_in[7];
    const int* dst_idx   = (const int*)d_in[8];
    float* out = (float*)d_out;

    char* ws = (char*)d_ws;
    unsigned short* nft = (unsigned short*)(ws);               // 51,200,000
    unsigned short* xb  = (unsigned short*)(ws + 51200000);    // 25,600,000
    unsigned short* Qt  = (unsigned short*)(ws + 76800000);    // 131,072
    unsigned short* Wt  = (unsigned short*)(ws + 76931072);    // 262,144
    int* counts    = (int*)(ws + 77193216);                    // 100,000
    int* offsets   = (int*)(ws + 77293216);                    // 100,004
    int* edge_list = (int*)(ws + 77393220);                    // 1,200,000 (~78.6 MB)

    hipMemsetAsync(counts, 0, N_DST * sizeof(int), stream);

    cast_weights<<<768, 256, 0, stream>>>(Q_w, W_w, Qt, Wt);
    hist_kernel<<<(N_EDGE + 255) / 256, 256, 0, stream>>>(dst_idx, counts);
    scan_kernel<<<1, 1024, 0, stream>>>(counts, offsets, N_DST);
    scatter_kernel<<<(N_EDGE + 255) / 256, 256, 0, stream>>>(dst_idx, offsets, counts, edge_list);

    gemm_pipe<256, true, false><<<(N_SRC + 63) / 64, 256, 0, stream>>>(
        h_src, nullptr, Qt, Q_b, nft, nullptr, N_SRC);

    aggregate_kernel<<<N_DST / 4, 256, 0, stream>>>(
        nft, h_dst, weights, src_idx, edge_list, offsets, xb);

    gemm_pipe<512, false, true><<<(N_DST + 63) / 64, 256, 0, stream>>>(
        nullptr, xb, Wt, W_b, nullptr, out, N_DST);

    (void)in_sizes; (void)n_in; (void)out_size; (void)ws_size;
}